// Round 5
// baseline (177.469 us; speedup 1.0000x reference)
//
#include <hip/hip_runtime.h>

#define BATCH   131072
#define NHID    128
#define KDIM    256     // n_in + n_hid
#define BM      32      // batch rows per tile
#define TPB     512     // 8 waves
#define NBLK    256     // persistent blocks (1 per CU)
#define NTILE   (BATCH / BM)     // 4096
#define TPBLK   (NTILE / NBLK)   // 16 tiles per block

typedef __bf16 bf16_t;
typedef __bf16 bf16x4 __attribute__((ext_vector_type(4)));
typedef __bf16 bf16x8 __attribute__((ext_vector_type(8)));
typedef float  f32x4  __attribute__((ext_vector_type(4)));

// LDS-only barrier: make ds_writes visible without draining in-flight global
// loads (compiler's __syncthreads would emit s_waitcnt vmcnt(0) and kill the
// cross-tile HBM prefetch pipeline).
#define LDS_BARRIER() do { \
    asm volatile("s_waitcnt lgkmcnt(0)" ::: "memory"); \
    __builtin_amdgcn_s_barrier(); \
} while (0)

__device__ __forceinline__ float fsigmoid(float v) {
    return __builtin_amdgcn_rcpf(1.0f + __builtin_amdgcn_exp2f(v * -1.44269504f));
}
__device__ __forceinline__ float ftanh(float v) {
    return __builtin_fmaf(-2.0f,
        __builtin_amdgcn_rcpf(1.0f + __builtin_amdgcn_exp2f(v * 2.88539008f)), 1.0f);
}

// Pack W4p[p][k] (bf16) with p = w*64 + t*16 + c  ->  gate t, output col j = w*16 + c.
// Puts all 4 gates of an output column into the same lane's 4 col-fragments.
__global__ void prep_kernel(const float* __restrict__ Wf, const float* __restrict__ Wi,
                            const float* __restrict__ Wc, const float* __restrict__ Wo,
                            const float* __restrict__ bfp, const float* __restrict__ bip,
                            const float* __restrict__ bcp, const float* __restrict__ bop,
                            const float* __restrict__ Wfc,
                            bf16_t* __restrict__ W4p, float* __restrict__ b4p,
                            bf16_t* __restrict__ Wfcb)
{
    int id = blockIdx.x * 256 + threadIdx.x;
    if (id < 512 * 256) {
        int p = id >> 8, k = id & 255;
        int w = p >> 6, t = (p >> 4) & 3, c = p & 15;
        int j = w * 16 + c;
        const float* W = (t == 0) ? Wf : (t == 1) ? Wi : (t == 2) ? Wc : Wo;
        W4p[id] = (bf16_t)W[j * 256 + k];
        if (k == 0) {
            const float* bs = (t == 0) ? bfp : (t == 1) ? bip : (t == 2) ? bcp : bop;
            b4p[p] = bs[j];
        }
    } else {
        int id2 = id - 512 * 256;
        if (id2 < 128 * 128) Wfcb[id2] = (bf16_t)Wfc[id2];
    }
}

__global__ __launch_bounds__(TPB, 2) void lstm_fused(
    const float* __restrict__ x, const float* __restrict__ hidden, const float* __restrict__ ctx,
    const bf16_t* __restrict__ W4p, const float* __restrict__ b4p,
    const bf16_t* __restrict__ Wfcb, const float* __restrict__ bfc,
    float* __restrict__ out, float* __restrict__ hid_out, float* __restrict__ ctx_out)
{
    // As[2]: bf16 [32][256] XOR-swizzled (2x16 KB) ; Hs[2]: bf16 [32][128] (2x8 KB)
    __shared__ __align__(16) char lds[2 * 16384 + 2 * 8192];

    const int tid  = threadIdx.x;
    const int lane = tid & 63;
    const int wv   = tid >> 6;     // 0..7
    const int l16  = lane & 15;
    const int lq   = lane >> 4;    // 0..3
    const int jcol = wv * 16 + l16;
    const int tile0 = blockIdx.x * TPBLK;

    // stage-thread mapping: thread owns row r_s, four 4-float chunks at c_s*4 + i*64
    const int r_s = tid >> 4;      // 0..31
    const int c_s = tid & 15;
    const int swzS = (r_s & 7) << 4;
    const int swzA = (l16 & 7) << 4;

    // ---- resident weights: B1 = this wave's 64 packed gate-cols (128 VGPR) ----
    bf16x8 B1[32];   // [gt*8 + ks]
    {
        const bf16_t* Bp = W4p + (wv * 64 + l16) * 256 + lq * 8;
        #pragma unroll
        for (int gt = 0; gt < 4; ++gt)
            #pragma unroll
            for (int ks = 0; ks < 8; ++ks)
                B1[gt * 8 + ks] = *(const bf16x8*)(Bp + gt * 16 * 256 + ks * 32);
    }
    bf16x8 b2r[4];
    {
        const bf16_t* B2 = Wfcb + jcol * 128 + lq * 8;
        #pragma unroll
        for (int ks = 0; ks < 4; ++ks) b2r[ks] = *(const bf16x8*)(B2 + ks * 32);
    }
    const float bfv = b4p[wv * 64 +  0 + l16];
    const float biv = b4p[wv * 64 + 16 + l16];
    const float bcv = b4p[wv * 64 + 32 + l16];
    const float bov = b4p[wv * 64 + 48 + l16];
    const float bo2 = bfc[jcol];

    f32x4 sv0, sv1, sv2, sv3;   // in-flight stage regs (tile t+1's A)
    float ctxA[2][4];           // current tile's ctx
    float ctxB[2][4];           // next tile's ctx (in flight)

    // ---- prologue ----
    {
        const int grow = tile0 * BM + r_s;
        const float* hrow = hidden + (size_t)grow * NHID + c_s * 4;
        const float* xrow = x      + (size_t)grow * NHID + c_s * 4;
        sv0 = *(const f32x4*)(hrow);
        sv1 = *(const f32x4*)(hrow + 64);
        sv2 = *(const f32x4*)(xrow);
        sv3 = *(const f32x4*)(xrow + 64);
        char* A0 = lds;
        bf16x4 p0, p1, p2, p3;
        p0[0]=(bf16_t)sv0.x; p0[1]=(bf16_t)sv0.y; p0[2]=(bf16_t)sv0.z; p0[3]=(bf16_t)sv0.w;
        p1[0]=(bf16_t)sv1.x; p1[1]=(bf16_t)sv1.y; p1[2]=(bf16_t)sv1.z; p1[3]=(bf16_t)sv1.w;
        p2[0]=(bf16_t)sv2.x; p2[1]=(bf16_t)sv2.y; p2[2]=(bf16_t)sv2.z; p2[3]=(bf16_t)sv2.w;
        p3[0]=(bf16_t)sv3.x; p3[1]=(bf16_t)sv3.y; p3[2]=(bf16_t)sv3.z; p3[3]=(bf16_t)sv3.w;
        *(bf16x4*)(A0 + r_s * 512 + ((c_s * 8 +   0) ^ swzS)) = p0;
        *(bf16x4*)(A0 + r_s * 512 + ((c_s * 8 + 128) ^ swzS)) = p1;
        *(bf16x4*)(A0 + r_s * 512 + ((c_s * 8 + 256) ^ swzS)) = p2;
        *(bf16x4*)(A0 + r_s * 512 + ((c_s * 8 + 384) ^ swzS)) = p3;
    }
    {   // issue stage loads for tile 1
        const int grow = (tile0 + 1) * BM + r_s;
        const float* hrow = hidden + (size_t)grow * NHID + c_s * 4;
        const float* xrow = x      + (size_t)grow * NHID + c_s * 4;
        sv0 = *(const f32x4*)(hrow);
        sv1 = *(const f32x4*)(hrow + 64);
        sv2 = *(const f32x4*)(xrow);
        sv3 = *(const f32x4*)(xrow + 64);
    }
    {   // ctx for tiles 0 and 1
        const float* cp0 = ctx + (size_t)(tile0 * BM) * NHID + jcol;
        const float* cp1 = ctx + (size_t)((tile0 + 1) * BM) * NHID + jcol;
        #pragma unroll
        for (int m = 0; m < 2; ++m)
            #pragma unroll
            for (int j = 0; j < 4; ++j) {
                ctxA[m][j] = cp0[(m * 16 + lq * 4 + j) * NHID];
                ctxB[m][j] = cp1[(m * 16 + lq * 4 + j) * NHID];
            }
    }
    __syncthreads();   // cold prologue barrier (full drain OK once)

    for (int t = 0; t < TPBLK; ++t) {
        const int P = t & 1;
        const int row0 = (tile0 + t) * BM;
        char* Asb = lds + P * 16384;
        char* Hsb = lds + 32768 + P * 8192;

        // ---- GEMM1: B from registers, A from LDS ----
        f32x4 acc[2][4];
        #pragma unroll
        for (int m = 0; m < 2; ++m)
            #pragma unroll
            for (int gt = 0; gt < 4; ++gt)
                acc[m][gt] = f32x4{0.f, 0.f, 0.f, 0.f};

        #pragma unroll
        for (int ks = 0; ks < 8; ++ks) {
            const int kb = ks * 64 + lq * 16;
            bf16x8 a0 = *(const bf16x8*)(Asb + l16 * 512        + (kb ^ swzA));
            bf16x8 a1 = *(const bf16x8*)(Asb + (16 + l16) * 512 + (kb ^ swzA));
            #pragma unroll
            for (int gt = 0; gt < 4; ++gt) {
                acc[0][gt] = __builtin_amdgcn_mfma_f32_16x16x32_bf16(a0, B1[gt * 8 + ks], acc[0][gt], 0, 0, 0);
                acc[1][gt] = __builtin_amdgcn_mfma_f32_16x16x32_bf16(a1, B1[gt * 8 + ks], acc[1][gt], 0, 0, 0);
            }
        }

        // ---- fused LSTM elementwise (gates all in-lane) ----
        float* co = ctx_out + (size_t)row0 * NHID + jcol;
        float* ho = hid_out + (size_t)row0 * NHID + jcol;
        bf16_t hnb[8];
        #pragma unroll
        for (int m = 0; m < 2; ++m) {
            #pragma unroll
            for (int j = 0; j < 4; ++j) {
                const int off = (m * 16 + lq * 4 + j) * NHID;
                const float fv = fsigmoid(acc[m][0][j] + bfv);
                const float iv = fsigmoid(acc[m][1][j] + biv);
                const float cv = ftanh(acc[m][2][j] + bcv);
                const float ov = fsigmoid(acc[m][3][j] + bov);
                const float cn = fv * ctxA[m][j] + iv * cv;
                const float hn = ov * ftanh(cn);
                co[off] = cn;
                ho[off] = hn;
                hnb[m * 4 + j] = (bf16_t)hn;
            }
        }

        // ---- rotate ctx pipeline: ctxA <- ctxB ; issue ctxB <- tile t+2 ----
        {
            const int tn = (t + 2 < TPBLK) ? t + 2 : TPBLK - 1;
            const float* cp = ctx + (size_t)((tile0 + tn) * BM) * NHID + jcol;
            #pragma unroll
            for (int m = 0; m < 2; ++m)
                #pragma unroll
                for (int j = 0; j < 4; ++j) {
                    ctxA[m][j] = ctxB[m][j];
                    ctxB[m][j] = cp[(m * 16 + lq * 4 + j) * NHID];
                }
        }

        // ---- write Hs (hidden_new, bf16, swizzled) ----
        #pragma unroll
        for (int m = 0; m < 2; ++m)
            #pragma unroll
            for (int j = 0; j < 4; ++j) {
                const int r = m * 16 + lq * 4 + j;
                *(bf16_t*)(Hsb + r * 256 + ((jcol * 2) ^ ((r & 7) << 4))) = hnb[m * 4 + j];
            }

        // ---- stage write: tile t+1 (loaded last iter) -> As[P^1] ----
        {
            char* An = lds + (1 - P) * 16384;
            bf16x4 p0, p1, p2, p3;
            p0[0]=(bf16_t)sv0.x; p0[1]=(bf16_t)sv0.y; p0[2]=(bf16_t)sv0.z; p0[3]=(bf16_t)sv0.w;
            p1[0]=(bf16_t)sv1.x; p1[1]=(bf16_t)sv1.y; p1[2]=(bf16_t)sv1.z; p1[3]=(bf16_t)sv1.w;
            p2[0]=(bf16_t)sv2.x; p2[1]=(bf16_t)sv2.y; p2[2]=(bf16_t)sv2.z; p2[3]=(bf16_t)sv2.w;
            p3[0]=(bf16_t)sv3.x; p3[1]=(bf16_t)sv3.y; p3[2]=(bf16_t)sv3.z; p3[3]=(bf16_t)sv3.w;
            *(bf16x4*)(An + r_s * 512 + ((c_s * 8 +   0) ^ swzS)) = p0;
            *(bf16x4*)(An + r_s * 512 + ((c_s * 8 + 128) ^ swzS)) = p1;
            *(bf16x4*)(An + r_s * 512 + ((c_s * 8 + 256) ^ swzS)) = p2;
            *(bf16x4*)(An + r_s * 512 + ((c_s * 8 + 384) ^ swzS)) = p3;
        }

        // ---- issue stage loads for tile t+2 ----
        {
            const int ts = (t + 2 < TPBLK) ? t + 2 : TPBLK - 1;
            const int grow = (tile0 + ts) * BM + r_s;
            const float* hrow = hidden + (size_t)grow * NHID + c_s * 4;
            const float* xrow = x      + (size_t)grow * NHID + c_s * 4;
            sv0 = *(const f32x4*)(hrow);
            sv1 = *(const f32x4*)(hrow + 64);
            sv2 = *(const f32x4*)(xrow);
            sv3 = *(const f32x4*)(xrow + 64);
        }

        // LDS-only barrier: As[P^1] + Hs[P] visible; HBM prefetches stay in flight
        LDS_BARRIER();

        // ---- GEMM2: out = hidden_new @ Wfc^T + bfc ----
        f32x4 acc2[2];
        acc2[0] = f32x4{0.f, 0.f, 0.f, 0.f};
        acc2[1] = f32x4{0.f, 0.f, 0.f, 0.f};
        #pragma unroll
        for (int ks = 0; ks < 4; ++ks) {
            const int kb = ks * 64 + lq * 16;
            bf16x8 a0 = *(const bf16x8*)(Hsb + l16 * 256        + (kb ^ swzA));
            bf16x8 a1 = *(const bf16x8*)(Hsb + (16 + l16) * 256 + (kb ^ swzA));
            acc2[0] = __builtin_amdgcn_mfma_f32_16x16x32_bf16(a0, b2r[ks], acc2[0], 0, 0, 0);
            acc2[1] = __builtin_amdgcn_mfma_f32_16x16x32_bf16(a1, b2r[ks], acc2[1], 0, 0, 0);
        }
        float* oo = out + (size_t)row0 * NHID + jcol;
        #pragma unroll
        for (int m = 0; m < 2; ++m)
            #pragma unroll
            for (int j = 0; j < 4; ++j)
                oo[(m * 16 + lq * 4 + j) * NHID] = acc2[m][j] + bo2;
    }
}

extern "C" void kernel_launch(void* const* d_in, const int* in_sizes, int n_in,
                              void* d_out, int out_size, void* d_ws, size_t ws_size,
                              hipStream_t stream) {
    const float* x      = (const float*)d_in[0];
    const float* hidden = (const float*)d_in[1];
    const float* ctx    = (const float*)d_in[2];
    const float* Wf     = (const float*)d_in[3];
    const float* bfp    = (const float*)d_in[4];
    const float* Wi     = (const float*)d_in[5];
    const float* bip    = (const float*)d_in[6];
    const float* Wc     = (const float*)d_in[7];
    const float* bcp    = (const float*)d_in[8];
    const float* Wo     = (const float*)d_in[9];
    const float* bop    = (const float*)d_in[10];
    const float* Wfc    = (const float*)d_in[11];
    const float* bfc    = (const float*)d_in[12];

    bf16_t* W4p  = (bf16_t*)d_ws;                                   // 262144 B
    float*  b4p  = (float*)((char*)d_ws + 512 * 256 * 2);           // 2048 B
    bf16_t* Wfcb = (bf16_t*)((char*)d_ws + 512 * 256 * 2 + 2048);   // 32768 B

    prep_kernel<<<576, 256, 0, stream>>>(Wf, Wi, Wc, Wo, bfp, bip, bcp, bop, Wfc,
                                         W4p, b4p, Wfcb);

    float* outp = (float*)d_out;
    lstm_fused<<<NBLK, TPB, 0, stream>>>(
        x, hidden, ctx, W4p, b4p, Wfcb, bfc,
        outp,
        outp + (size_t)BATCH * NHID,
        outp + 2 * (size_t)BATCH * NHID);
}

// Round 6
// 117.037 us; speedup vs baseline: 1.5164x; 1.5164x over previous
//
#include <hip/hip_runtime.h>

#define BATCH   131072
#define NHID    128
#define KDIM    256     // n_in + n_hid
#define BM      32      // batch rows per tile
#define TPB     512     // 8 waves
#define NBLK    256     // persistent blocks (1 per CU)
#define NTILE   (BATCH / BM)     // 4096
#define TPBLK   (NTILE / NBLK)   // 16 tiles per block

typedef __bf16 bf16_t;
typedef __bf16 bf16x4 __attribute__((ext_vector_type(4)));
typedef __bf16 bf16x8 __attribute__((ext_vector_type(8)));
typedef float  f32x4  __attribute__((ext_vector_type(4)));

__device__ __forceinline__ float fsigmoid(float v) {
    return __builtin_amdgcn_rcpf(1.0f + __builtin_amdgcn_exp2f(v * -1.44269504f));
}
__device__ __forceinline__ float ftanh(float v) {
    return __builtin_fmaf(-2.0f,
        __builtin_amdgcn_rcpf(1.0f + __builtin_amdgcn_exp2f(v * 2.88539008f)), 1.0f);
}
__device__ __forceinline__ f32x4 vsig(f32x4 v) {
    f32x4 r;
    #pragma unroll
    for (int i = 0; i < 4; ++i) r[i] = fsigmoid(v[i]);
    return r;
}
__device__ __forceinline__ f32x4 vtanh(f32x4 v) {
    f32x4 r;
    #pragma unroll
    for (int i = 0; i < 4; ++i) r[i] = ftanh(v[i]);
    return r;
}

// Pack W4p[p][k] (bf16) with p = w*64 + t*16 + c  ->  gate t, output col j = w*16 + c.
__global__ void prep_kernel(const float* __restrict__ Wf, const float* __restrict__ Wi,
                            const float* __restrict__ Wc, const float* __restrict__ Wo,
                            const float* __restrict__ bfp, const float* __restrict__ bip,
                            const float* __restrict__ bcp, const float* __restrict__ bop,
                            const float* __restrict__ Wfc,
                            bf16_t* __restrict__ W4p, float* __restrict__ b4p,
                            bf16_t* __restrict__ Wfcb)
{
    int id = blockIdx.x * 256 + threadIdx.x;
    if (id < 512 * 256) {
        int p = id >> 8, k = id & 255;
        int w = p >> 6, t = (p >> 4) & 3, c = p & 15;
        int j = w * 16 + c;
        const float* W = (t == 0) ? Wf : (t == 1) ? Wi : (t == 2) ? Wc : Wo;
        W4p[id] = (bf16_t)W[j * 256 + k];
        if (k == 0) {
            const float* bs = (t == 0) ? bfp : (t == 1) ? bip : (t == 2) ? bcp : bop;
            b4p[p] = bs[j];
        }
    } else {
        int id2 = id - 512 * 256;
        if (id2 < 128 * 128) Wfcb[id2] = (bf16_t)Wfc[id2];
    }
}

__global__ __launch_bounds__(TPB, 2) void lstm_fused(
    const float* __restrict__ x, const float* __restrict__ hidden, const float* __restrict__ ctx,
    const bf16_t* __restrict__ W4p, const float* __restrict__ b4p,
    const bf16_t* __restrict__ Wfcb, const float* __restrict__ bfc,
    float* __restrict__ out, float* __restrict__ hid_out, float* __restrict__ ctx_out)
{
    // As[2]: bf16 [32][256] XOR-swizzled (2x16 KB) ; Hs[2]: bf16 [32][128] (2x8 KB)
    __shared__ __align__(16) char lds[2 * 16384 + 2 * 8192];

    const int tid  = threadIdx.x;
    const int lane = tid & 63;
    const int wv   = tid >> 6;     // 0..7
    const int l16  = lane & 15;
    const int lq   = lane >> 4;    // 0..3
    const int tile0 = blockIdx.x * TPBLK;
    const int colb  = wv * 16 + lq * 4;     // this lane's 4 consecutive output cols
    const int swzA  = (l16 & 7) << 4;       // swizzle for LDS reads (row = l16 mod 16)

    // stage-thread mapping
    const int r_s = tid >> 4;      // 0..31
    const int c_s = tid & 15;
    const int swzS = (r_s & 7) << 4;

    // ---- resident weights: B1 = this wave's 64 packed gate-rows (128 VGPR) ----
    // A-operand of transposed GEMM1: frag pm covers p-rows wv*64 + pm*16 + l16.
    bf16x8 B1[32];   // [pm*8 + ks]
    {
        const bf16_t* Bp = W4p + (wv * 64 + l16) * 256 + lq * 8;
        #pragma unroll
        for (int pm = 0; pm < 4; ++pm)
            #pragma unroll
            for (int ks = 0; ks < 8; ++ks)
                B1[pm * 8 + ks] = *(const bf16x8*)(Bp + pm * 16 * 256 + ks * 32);
    }
    bf16x8 b2r[4];
    {
        const bf16_t* B2 = Wfcb + (wv * 16 + l16) * 128 + lq * 8;
        #pragma unroll
        for (int ks = 0; ks < 4; ++ks) b2r[ks] = *(const bf16x8*)(B2 + ks * 32);
    }
    // bias vectors for the 4 consecutive cols (p = wv*64 + t*16 + colb lane part)
    const f32x4 bf4 = *(const f32x4*)(b4p + wv * 64 +  0 + lq * 4);
    const f32x4 bi4 = *(const f32x4*)(b4p + wv * 64 + 16 + lq * 4);
    const f32x4 bc4 = *(const f32x4*)(b4p + wv * 64 + 32 + lq * 4);
    const f32x4 bo4 = *(const f32x4*)(b4p + wv * 64 + 48 + lq * 4);
    const f32x4 bfc4 = *(const f32x4*)(bfc + colb);

    f32x4 sv0, sv1, sv2, sv3;   // stage regs for tile t+1 (issued at iter top)
    f32x4 ctxA[2], ctxB[2];     // ctx for tile t / t+1 (per bn: batch row bn*16+l16)

    // ---- prologue: stage tile0 -> As[0]; ctxA <- tile0 ----
    {
        const int grow = tile0 * BM + r_s;
        const float* hrow = hidden + (size_t)grow * NHID + c_s * 4;
        const float* xrow = x      + (size_t)grow * NHID + c_s * 4;
        f32x4 t0 = *(const f32x4*)(hrow);
        f32x4 t1 = *(const f32x4*)(hrow + 64);
        f32x4 t2 = *(const f32x4*)(xrow);
        f32x4 t3 = *(const f32x4*)(xrow + 64);
        char* A0 = lds;
        bf16x4 p0, p1, p2, p3;
        p0[0]=(bf16_t)t0.x; p0[1]=(bf16_t)t0.y; p0[2]=(bf16_t)t0.z; p0[3]=(bf16_t)t0.w;
        p1[0]=(bf16_t)t1.x; p1[1]=(bf16_t)t1.y; p1[2]=(bf16_t)t1.z; p1[3]=(bf16_t)t1.w;
        p2[0]=(bf16_t)t2.x; p2[1]=(bf16_t)t2.y; p2[2]=(bf16_t)t2.z; p2[3]=(bf16_t)t2.w;
        p3[0]=(bf16_t)t3.x; p3[1]=(bf16_t)t3.y; p3[2]=(bf16_t)t3.z; p3[3]=(bf16_t)t3.w;
        *(bf16x4*)(A0 + r_s * 512 + ((c_s * 8 +   0) ^ swzS)) = p0;
        *(bf16x4*)(A0 + r_s * 512 + ((c_s * 8 + 128) ^ swzS)) = p1;
        *(bf16x4*)(A0 + r_s * 512 + ((c_s * 8 + 256) ^ swzS)) = p2;
        *(bf16x4*)(A0 + r_s * 512 + ((c_s * 8 + 384) ^ swzS)) = p3;
    }
    {
        const float* cp = ctx + (size_t)(tile0 * BM) * NHID + colb;
        ctxA[0] = *(const f32x4*)(cp + (size_t)l16 * NHID);
        ctxA[1] = *(const f32x4*)(cp + (size_t)(16 + l16) * NHID);
    }
    __syncthreads();

    for (int t = 0; t < TPBLK; ++t) {
        const int P = t & 1;
        const int row0 = (tile0 + t) * BM;
        char* Asb = lds + P * 16384;
        char* Hsb = lds + 32768 + P * 8192;

        // ---- TOP: issue next tile's HBM loads (latency hides under GEMM1+epi) ----
        {
            const int tn = (t + 1 < TPBLK) ? t + 1 : TPBLK - 1;
            const int grow = (tile0 + tn) * BM + r_s;
            const float* hrow = hidden + (size_t)grow * NHID + c_s * 4;
            const float* xrow = x      + (size_t)grow * NHID + c_s * 4;
            sv0 = *(const f32x4*)(hrow);
            sv1 = *(const f32x4*)(hrow + 64);
            sv2 = *(const f32x4*)(xrow);
            sv3 = *(const f32x4*)(xrow + 64);
            const float* cp = ctx + (size_t)((tile0 + tn) * BM) * NHID + colb;
            ctxB[0] = *(const f32x4*)(cp + (size_t)l16 * NHID);
            ctxB[1] = *(const f32x4*)(cp + (size_t)(16 + l16) * NHID);
        }

        // ---- GEMM1 (transposed): gates^T = W4 . A^T ; acc[pm][bn] ----
        // A-operand: B1 (weights, resident). B-operand: As rows (batch).
        f32x4 acc[4][2];
        #pragma unroll
        for (int pm = 0; pm < 4; ++pm) {
            acc[pm][0] = f32x4{0.f, 0.f, 0.f, 0.f};
            acc[pm][1] = f32x4{0.f, 0.f, 0.f, 0.f};
        }
        #pragma unroll
        for (int ks = 0; ks < 8; ++ks) {
            const int kb = ks * 64 + lq * 16;
            bf16x8 a0 = *(const bf16x8*)(Asb + l16 * 512        + (kb ^ swzA));
            bf16x8 a1 = *(const bf16x8*)(Asb + (16 + l16) * 512 + (kb ^ swzA));
            #pragma unroll
            for (int pm = 0; pm < 4; ++pm) {
                acc[pm][0] = __builtin_amdgcn_mfma_f32_16x16x32_bf16(B1[pm * 8 + ks], a0, acc[pm][0], 0, 0, 0);
                acc[pm][1] = __builtin_amdgcn_mfma_f32_16x16x32_bf16(B1[pm * 8 + ks], a1, acc[pm][1], 0, 0, 0);
            }
        }

        // ---- fused LSTM elementwise, fully vectorized (4 cols per lane) ----
        #pragma unroll
        for (int bn = 0; bn < 2; ++bn) {
            const size_t grow = (size_t)(row0 + bn * 16 + l16) * NHID + colb;
            const f32x4 fv = vsig(acc[0][bn] + bf4);
            const f32x4 iv = vsig(acc[1][bn] + bi4);
            const f32x4 cv = vtanh(acc[2][bn] + bc4);
            const f32x4 ov = vsig(acc[3][bn] + bo4);
            const f32x4 cn = fv * ctxA[bn] + iv * cv;
            const f32x4 hn = ov * vtanh(cn);
            *(f32x4*)(ctx_out + grow) = cn;
            *(f32x4*)(hid_out + grow) = hn;
            bf16x4 hb;
            hb[0] = (bf16_t)hn.x; hb[1] = (bf16_t)hn.y;
            hb[2] = (bf16_t)hn.z; hb[3] = (bf16_t)hn.w;
            const int rh = bn * 16 + l16;
            *(bf16x4*)(Hsb + rh * 256 + ((wv * 32 + lq * 8) ^ ((rh & 7) << 4))) = hb;
        }
        ctxA[0] = ctxB[0];
        ctxA[1] = ctxB[1];

        // ---- stage write: tile t+1 (issued at top) -> As[P^1] ----
        {
            char* An = lds + (1 - P) * 16384;
            bf16x4 p0, p1, p2, p3;
            p0[0]=(bf16_t)sv0.x; p0[1]=(bf16_t)sv0.y; p0[2]=(bf16_t)sv0.z; p0[3]=(bf16_t)sv0.w;
            p1[0]=(bf16_t)sv1.x; p1[1]=(bf16_t)sv1.y; p1[2]=(bf16_t)sv1.z; p1[3]=(bf16_t)sv1.w;
            p2[0]=(bf16_t)sv2.x; p2[1]=(bf16_t)sv2.y; p2[2]=(bf16_t)sv2.z; p2[3]=(bf16_t)sv2.w;
            p3[0]=(bf16_t)sv3.x; p3[1]=(bf16_t)sv3.y; p3[2]=(bf16_t)sv3.z; p3[3]=(bf16_t)sv3.w;
            *(bf16x4*)(An + r_s * 512 + ((c_s * 8 +   0) ^ swzS)) = p0;
            *(bf16x4*)(An + r_s * 512 + ((c_s * 8 + 128) ^ swzS)) = p1;
            *(bf16x4*)(An + r_s * 512 + ((c_s * 8 + 256) ^ swzS)) = p2;
            *(bf16x4*)(An + r_s * 512 + ((c_s * 8 + 384) ^ swzS)) = p3;
        }

        __syncthreads();   // As[P^1] + Hs[P] visible (loads were issued ~2000cy ago)

        // ---- GEMM2 (transposed): out^T = Wfc . h^T ----
        f32x4 acc2[2];
        acc2[0] = f32x4{0.f, 0.f, 0.f, 0.f};
        acc2[1] = f32x4{0.f, 0.f, 0.f, 0.f};
        #pragma unroll
        for (int ks = 0; ks < 4; ++ks) {
            const int kb = ks * 64 + lq * 16;
            bf16x8 h0 = *(const bf16x8*)(Hsb + l16 * 256        + (kb ^ swzA));
            bf16x8 h1 = *(const bf16x8*)(Hsb + (16 + l16) * 256 + (kb ^ swzA));
            acc2[0] = __builtin_amdgcn_mfma_f32_16x16x32_bf16(b2r[ks], h0, acc2[0], 0, 0, 0);
            acc2[1] = __builtin_amdgcn_mfma_f32_16x16x32_bf16(b2r[ks], h1, acc2[1], 0, 0, 0);
        }
        #pragma unroll
        for (int bn = 0; bn < 2; ++bn) {
            const size_t grow = (size_t)(row0 + bn * 16 + l16) * NHID + colb;
            *(f32x4*)(out + grow) = acc2[bn] + bfc4;
        }
    }
}

extern "C" void kernel_launch(void* const* d_in, const int* in_sizes, int n_in,
                              void* d_out, int out_size, void* d_ws, size_t ws_size,
                              hipStream_t stream) {
    const float* x      = (const float*)d_in[0];
    const float* hidden = (const float*)d_in[1];
    const float* ctx    = (const float*)d_in[2];
    const float* Wf     = (const float*)d_in[3];
    const float* bfp    = (const float*)d_in[4];
    const float* Wi     = (const float*)d_in[5];
    const float* bip    = (const float*)d_in[6];
    const float* Wc     = (const float*)d_in[7];
    const float* bcp    = (const float*)d_in[8];
    const float* Wo     = (const float*)d_in[9];
    const float* bop    = (const float*)d_in[10];
    const float* Wfc    = (const float*)d_in[11];
    const float* bfc    = (const float*)d_in[12];

    bf16_t* W4p  = (bf16_t*)d_ws;                                   // 262144 B
    float*  b4p  = (float*)((char*)d_ws + 512 * 256 * 2);           // 2048 B
    bf16_t* Wfcb = (bf16_t*)((char*)d_ws + 512 * 256 * 2 + 2048);   // 32768 B

    prep_kernel<<<576, 256, 0, stream>>>(Wf, Wi, Wc, Wo, bfp, bip, bcp, bop, Wfc,
                                         W4p, b4p, Wfcb);

    float* outp = (float*)d_out;
    lstm_fused<<<NBLK, TPB, 0, stream>>>(
        x, hidden, ctx, W4p, b4p, Wfcb, bfc,
        outp,
        outp + (size_t)BATCH * NHID,
        outp + 2 * (size_t)BATCH * NHID);
}